// Round 9
// baseline (86.365 us; speedup 1.0000x reference)
//
#include <hip/hip_runtime.h>
#include <hip/hip_bf16.h>

#define B_ 64
#define S_ 128
#define D_ 1024
#define O_ 1024
#define L_ 16

typedef __bf16 bf16x8 __attribute__((ext_vector_type(8)));
typedef float f32x4 __attribute__((ext_vector_type(4)));

// 8 floats -> bf16x8 via scalar casts; compiler pairs into v_cvt_pk_bf16_f32.
__device__ __forceinline__ bf16x8 cvt8(float4 a, float4 b) {
    bf16x8 r;
    r[0] = (__bf16)a.x; r[1] = (__bf16)a.y; r[2] = (__bf16)a.z; r[3] = (__bf16)a.w;
    r[4] = (__bf16)b.x; r[5] = (__bf16)b.y; r[6] = (__bf16)b.z; r[7] = (__bf16)b.w;
    return r;
}

// Single fused kernel, fixed pipeline: single-barrier double-buffered LDS.
// Per iteration: issue fp32 loads(kt+1) -> MFMA on buf[cur] -> cvt+ds_write
// into buf[cur^1] -> ONE barrier. No barrier between load issue and use, so
// the scheduler hoists loads above the MFMA cluster (verify: VGPR >= 110).
// Tile M=128 (2s x 64b) x N=128, BK=64, 8 waves (2 wm x 4 wn), 64x32/wave.
__global__ __launch_bounds__(512, 4) void moshi_fused(
    const float* __restrict__ x, const int* __restrict__ lidx,
    const float* __restrict__ w, float* __restrict__ out) {

    // [buf][ lw: 128x64 bf16 swizzled (16 KB) | lx: 2x(64x64) bf16 (16 KB) ]
    __shared__ __align__(16) unsigned char buf[2][32768];

    const int tid = threadIdx.x, lane = tid & 63, wid = tid >> 6;

    // ---- pair scan, aliased into buf[0] (consumed before any staging) ----
    int* occ  = (int*)&buf[0][0];      // [16][128]
    int* cnts = (int*)&buf[0][8192];   // [16]
    if (tid < 16) {
        int c = 0;
        for (int s = 0; s < S_; ++s)
            if (lidx[s] == tid) occ[tid * 128 + c++] = s;
        cnts[tid] = c;
    }
    __syncthreads();

    // bijective XCD-chunk swizzle: grid 576 = 8 chunks of 72 (9 pairs x 8 nt)
    const int bid = (blockIdx.x & 7) * 72 + (blockIdx.x >> 3);
    const int pi = bid >> 3;
    const int nt = bid & 7;

    int np = 0, l = -1, j = 0;
    #pragma unroll
    for (int m = 0; m < 16; ++m) {
        int p = (cnts[m] + 1) >> 1;
        if (l < 0 && pi < np + p) { l = m; j = pi - np; }
        np += p;
    }
    const bool active = (pi < np);          // block-uniform
    int s0 = 0, s1 = 0;
    if (active) {
        int cl = cnts[l];
        s0 = occ[l * 128 + 2 * j];
        s1 = occ[l * 128 + ((2 * j + 1 < cl) ? (2 * j + 1) : (2 * j))];
    }
    __syncthreads();                        // occ reads done before staging
    if (!active) return;                    // whole block exits: no barrier hazard

    // ---- staging addresses (byte offsets within one 32 KB buffer) ----
    // W: thread t -> row t/4 (o), quad q=t&3 (16 consecutive floats).
    const int wrow = tid >> 2;
    const int q    = tid & 3;
    const float* wsrc = w + ((size_t)(l * O_ + nt * 128 + wrow)) * D_ + q * 16;
    const int key_w = (wrow & 7) << 4;
    const int c0    = q * 32;                       // bf16 byte col of quad
    const int off_w0 = wrow * 128 + (c0 ^ key_w);
    const int off_w1 = wrow * 128 + ((c0 + 16) ^ key_w);
    // x: thread t -> s-half t/256, b-row (t/4)&63, quad q.
    const int shalf = tid >> 8;
    const int xb    = (tid >> 2) & 63;
    const int s_st  = shalf ? s1 : s0;
    const float* xsrc = x + ((size_t)(xb * S_ + s_st)) * D_ + q * 16;
    const int key_x = (xb & 7) << 4;
    const int off_x0 = 16384 + shalf * 8192 + xb * 128 + (c0 ^ key_x);
    const int off_x1 = 16384 + shalf * 8192 + xb * 128 + ((c0 + 16) ^ key_x);

    // ---- fragment read addressing (proven R6 mapping) ----
    const int wm = wid >> 2, wn = wid & 3;
    const int swz = (lane & 7) << 4;
    const int kb  = (lane >> 4) << 4;
    const int a_base = 16384 + (wm * 64 + (lane & 15)) * 128 + kb;   // x rows
    const int b_base = (wn * 32 + (lane & 15)) * 128 + kb;           // W rows

    f32x4 acc[4][2];
    #pragma unroll
    for (int i = 0; i < 4; ++i)
        #pragma unroll
        for (int jj = 0; jj < 2; ++jj) acc[i][jj] = (f32x4)0.0f;

    // ---- prologue: stage tile 0 into buf[0] ----
    {
        const float4* pw = reinterpret_cast<const float4*>(wsrc);
        const float4* px = reinterpret_cast<const float4*>(xsrc);
        float4 a0 = pw[0], a1 = pw[1], a2 = pw[2], a3 = pw[3];
        float4 b0 = px[0], b1 = px[1], b2 = px[2], b3 = px[3];
        *reinterpret_cast<bf16x8*>(&buf[0][off_w0]) = cvt8(a0, a1);
        *reinterpret_cast<bf16x8*>(&buf[0][off_w1]) = cvt8(a2, a3);
        *reinterpret_cast<bf16x8*>(&buf[0][off_x0]) = cvt8(b0, b1);
        *reinterpret_cast<bf16x8*>(&buf[0][off_x1]) = cvt8(b2, b3);
    }
    __syncthreads();

    int cur = 0;
    #pragma unroll 1
    for (int kt = 0; kt < 15; ++kt) {
        const unsigned char* bc = buf[cur];
        unsigned char* bn = buf[cur ^ 1];
        // 1) issue next tile's loads — same scheduling region as the MFMAs
        const float4* pw = reinterpret_cast<const float4*>(wsrc + (kt + 1) * 64);
        const float4* px = reinterpret_cast<const float4*>(xsrc + (kt + 1) * 64);
        float4 a0 = pw[0], a1 = pw[1], a2 = pw[2], a3 = pw[3];
        float4 b0 = px[0], b1 = px[1], b2 = px[2], b3 = px[3];
        // 2) MFMA on current buffer (independent of the loads above)
        #pragma unroll
        for (int kk = 0; kk < 2; ++kk) {
            bf16x8 af[4], bfr[2];
            #pragma unroll
            for (int mi = 0; mi < 4; ++mi)
                af[mi] = *reinterpret_cast<const bf16x8*>(
                    bc + (((a_base + kk * 64) ^ swz) + mi * 2048));
            #pragma unroll
            for (int ni = 0; ni < 2; ++ni)
                bfr[ni] = *reinterpret_cast<const bf16x8*>(
                    bc + (((b_base + kk * 64) ^ swz) + ni * 2048));
            #pragma unroll
            for (int mi = 0; mi < 4; ++mi)
                #pragma unroll
                for (int ni = 0; ni < 2; ++ni)
                    acc[mi][ni] = __builtin_amdgcn_mfma_f32_16x16x32_bf16(
                        af[mi], bfr[ni], acc[mi][ni], 0, 0, 0);
        }
        // 3) convert + write next tile (vmcnt wait lands here, after MFMAs)
        *reinterpret_cast<bf16x8*>(bn + off_w0) = cvt8(a0, a1);
        *reinterpret_cast<bf16x8*>(bn + off_w1) = cvt8(a2, a3);
        *reinterpret_cast<bf16x8*>(bn + off_x0) = cvt8(b0, b1);
        *reinterpret_cast<bf16x8*>(bn + off_x1) = cvt8(b2, b3);
        // 4) one barrier: my tile-(kt+1) writes visible; all reads of tile kt done
        __syncthreads();
        cur ^= 1;
    }
    // final tile (kt = 15): compute only
    {
        const unsigned char* bc = buf[cur];
        #pragma unroll
        for (int kk = 0; kk < 2; ++kk) {
            bf16x8 af[4], bfr[2];
            #pragma unroll
            for (int mi = 0; mi < 4; ++mi)
                af[mi] = *reinterpret_cast<const bf16x8*>(
                    bc + (((a_base + kk * 64) ^ swz) + mi * 2048));
            #pragma unroll
            for (int ni = 0; ni < 2; ++ni)
                bfr[ni] = *reinterpret_cast<const bf16x8*>(
                    bc + (((b_base + kk * 64) ^ swz) + ni * 2048));
            #pragma unroll
            for (int mi = 0; mi < 4; ++mi)
                #pragma unroll
                for (int ni = 0; ni < 2; ++ni)
                    acc[mi][ni] = __builtin_amdgcn_mfma_f32_16x16x32_bf16(
                        af[mi], bfr[ni], acc[mi][ni], 0, 0, 0);
        }
    }

    // ---- epilogue: C/D col = lane&15 (o), row = (lane>>4)*4 + reg (b) ----
    const int s_sel = wm ? s1 : s0;
    const int col0 = nt * 128 + wn * 32 + (lane & 15);
    const int r0 = (lane >> 4) << 2;
    #pragma unroll
    for (int mi = 0; mi < 4; ++mi)
        #pragma unroll
        for (int ni = 0; ni < 2; ++ni)
            #pragma unroll
            for (int r = 0; r < 4; ++r) {
                int b = mi * 16 + r0 + r;
                out[((size_t)b * S_ + s_sel) * O_ + col0 + ni * 16] = acc[mi][ni][r];
            }
}

extern "C" void kernel_launch(void* const* d_in, const int* in_sizes, int n_in,
                              void* d_out, int out_size, void* d_ws, size_t ws_size,
                              hipStream_t stream) {
    const float* x  = (const float*)d_in[0];
    const int* lidx = (const int*)d_in[1];
    const float* w  = (const float*)d_in[2];
    float* out      = (float*)d_out;
    (void)d_ws; (void)ws_size;
    // 72 pair slots x 8 n-tiles; blocks beyond npairs exit early (uniform)
    moshi_fused<<<dim3(72 * 8), dim3(512), 0, stream>>>(x, lidx, w, out);
}

// Round 10
// 86.022 us; speedup vs baseline: 1.0040x; 1.0040x over previous
//
#include <hip/hip_runtime.h>
#include <hip/hip_bf16.h>

#define B_ 64
#define S_ 128
#define D_ 1024
#define O_ 1024
#define L_ 16

typedef __bf16 bf16x8 __attribute__((ext_vector_type(8)));
typedef float f32x4 __attribute__((ext_vector_type(4)));

// asm global load: cannot be sunk by the scheduler; result valid only after
// s_waitcnt vmcnt. "memory" clobber keeps ds/vm ops from crossing it.
__device__ __forceinline__ f32x4 gload4(const float* p) {
    f32x4 r;
    asm volatile("global_load_dwordx4 %0, %1, off" : "=v"(r) : "v"(p) : "memory");
    return r;
}

__device__ __forceinline__ bf16x8 cvt8(f32x4 a, f32x4 b) {
    bf16x8 r;
    r[0] = (__bf16)a[0]; r[1] = (__bf16)a[1]; r[2] = (__bf16)a[2]; r[3] = (__bf16)a[3];
    r[4] = (__bf16)b[0]; r[5] = (__bf16)b[1]; r[6] = (__bf16)b[2]; r[7] = (__bf16)b[3];
    return r;
}

// Fused kernel, asm-enforced pipeline. Tile M=128 (2s x 64b) x N=128, BK=64,
// 8 waves (2 wm x 4 wn), 64x32 per wave. Single 32 KB LDS buffer; raw
// s_barrier (no vmcnt auto-drain); per iter:
//   asm-load(kt+1) -> ds_read frags(kt) -> lgkmcnt(0) -> barrier ->
//   MFMA (loads in flight) -> vmcnt(0) -> cvt+ds_write(kt+1) -> lgkmcnt(0) -> barrier
__global__ __launch_bounds__(512, 4) void moshi_fused(
    const float* __restrict__ x, const int* __restrict__ lidx,
    const float* __restrict__ w, float* __restrict__ out) {

    __shared__ __align__(16) unsigned char buf[32768];  // [lw 16K | lx 16K]

    const int tid = threadIdx.x, lane = tid & 63, wid = tid >> 6;

    // ---- pair scan, aliased into buf (consumed before any staging) ----
    int* occ  = (int*)&buf[0];       // [16][128]
    int* cnts = (int*)&buf[8192];    // [16]
    if (tid < 16) {
        int c = 0;
        for (int s = 0; s < S_; ++s)
            if (lidx[s] == tid) occ[tid * 128 + c++] = s;
        cnts[tid] = c;
    }
    __syncthreads();

    // bijective XCD-chunk swizzle: grid 576 = 8 chunks of 72 (9 pairs x 8 nt)
    const int bid = (blockIdx.x & 7) * 72 + (blockIdx.x >> 3);
    const int pi = bid >> 3;
    const int nt = bid & 7;

    int np = 0, l = -1, j = 0;
    #pragma unroll
    for (int m = 0; m < 16; ++m) {
        int p = (cnts[m] + 1) >> 1;
        if (l < 0 && pi < np + p) { l = m; j = pi - np; }
        np += p;
    }
    const bool active = (pi < np);          // block-uniform
    int s0 = 0, s1 = 0;
    if (active) {
        int cl = cnts[l];
        s0 = occ[l * 128 + 2 * j];
        s1 = occ[l * 128 + ((2 * j + 1 < cl) ? (2 * j + 1) : (2 * j))];
    }
    __syncthreads();                        // occ reads done before staging
    if (!active) return;                    // uniform exit: barrier counts match

    // ---- staging addresses ----
    const int wrow = tid >> 2;
    const int q    = tid & 3;
    const float* wsrc = w + ((size_t)(l * O_ + nt * 128 + wrow)) * D_ + q * 16;
    const int key_w = (wrow & 7) << 4;
    const int c0    = q * 32;
    const int off_w0 = wrow * 128 + (c0 ^ key_w);
    const int off_w1 = wrow * 128 + ((c0 + 16) ^ key_w);
    const int shalf = tid >> 8;
    const int xb    = (tid >> 2) & 63;
    const int s_st  = shalf ? s1 : s0;
    const float* xsrc = x + ((size_t)(xb * S_ + s_st)) * D_ + q * 16;
    const int key_x = (xb & 7) << 4;
    const int off_x0 = 16384 + shalf * 8192 + xb * 128 + (c0 ^ key_x);
    const int off_x1 = 16384 + shalf * 8192 + xb * 128 + ((c0 + 16) ^ key_x);

    // ---- fragment read addressing (proven mapping) ----
    const int wm = wid >> 2, wn = wid & 3;
    const int swz = (lane & 7) << 4;
    const int kb  = (lane >> 4) << 4;
    const int a_base = 16384 + (wm * 64 + (lane & 15)) * 128 + kb;   // x rows
    const int b_base = (wn * 32 + (lane & 15)) * 128 + kb;           // W rows

    f32x4 acc[4][2];
    #pragma unroll
    for (int i = 0; i < 4; ++i)
        #pragma unroll
        for (int jj = 0; jj < 2; ++jj) acc[i][jj] = (f32x4)0.0f;

    // ---- prologue: stage tile 0 ----
    {
        f32x4 a0 = gload4(wsrc + 0),  a1 = gload4(wsrc + 4);
        f32x4 a2 = gload4(wsrc + 8),  a3 = gload4(wsrc + 12);
        f32x4 b0 = gload4(xsrc + 0),  b1 = gload4(xsrc + 4);
        f32x4 b2 = gload4(xsrc + 8),  b3 = gload4(xsrc + 12);
        asm volatile("s_waitcnt vmcnt(0)" ::: "memory");
        __builtin_amdgcn_sched_barrier(0);
        *reinterpret_cast<bf16x8*>(&buf[off_w0]) = cvt8(a0, a1);
        *reinterpret_cast<bf16x8*>(&buf[off_w1]) = cvt8(a2, a3);
        *reinterpret_cast<bf16x8*>(&buf[off_x0]) = cvt8(b0, b1);
        *reinterpret_cast<bf16x8*>(&buf[off_x1]) = cvt8(b2, b3);
    }
    __syncthreads();   // auto-drain fine here (nothing in flight we need alive)

    #pragma unroll 1
    for (int kt = 0; kt < 15; ++kt) {
        // 1) issue next tile's loads — pinned at this point by asm volatile
        const float* pw = wsrc + (kt + 1) * 64;
        const float* px = xsrc + (kt + 1) * 64;
        f32x4 a0 = gload4(pw + 0),  a1 = gload4(pw + 4);
        f32x4 a2 = gload4(pw + 8),  a3 = gload4(pw + 12);
        f32x4 b0 = gload4(px + 0),  b1 = gload4(px + 4);
        f32x4 b2 = gload4(px + 8),  b3 = gload4(px + 12);

        // 2) pull current tile's fragments from LDS
        bf16x8 af[2][4], bfr[2][2];
        #pragma unroll
        for (int kk = 0; kk < 2; ++kk) {
            #pragma unroll
            for (int mi = 0; mi < 4; ++mi)
                af[kk][mi] = *reinterpret_cast<const bf16x8*>(
                    &buf[((a_base + kk * 64) ^ swz) + mi * 2048]);
            #pragma unroll
            for (int ni = 0; ni < 2; ++ni)
                bfr[kk][ni] = *reinterpret_cast<const bf16x8*>(
                    &buf[((b_base + kk * 64) ^ swz) + ni * 2048]);
        }
        asm volatile("s_waitcnt lgkmcnt(0)" ::: "memory");
        __builtin_amdgcn_sched_barrier(0);
        __builtin_amdgcn_s_barrier();      // all waves finished reading tile kt

        // 3) MFMA cluster — global loads still in flight underneath
        __builtin_amdgcn_s_setprio(1);
        #pragma unroll
        for (int kk = 0; kk < 2; ++kk)
            #pragma unroll
            for (int mi = 0; mi < 4; ++mi)
                #pragma unroll
                for (int ni = 0; ni < 2; ++ni)
                    acc[mi][ni] = __builtin_amdgcn_mfma_f32_16x16x32_bf16(
                        af[kk][mi], bfr[kk][ni], acc[mi][ni], 0, 0, 0);
        __builtin_amdgcn_s_setprio(0);

        // 4) loads arrived; cvt must not hoist above this wait (rule #18)
        asm volatile("s_waitcnt vmcnt(0)" ::: "memory");
        __builtin_amdgcn_sched_barrier(0);
        *reinterpret_cast<bf16x8*>(&buf[off_w0]) = cvt8(a0, a1);
        *reinterpret_cast<bf16x8*>(&buf[off_w1]) = cvt8(a2, a3);
        *reinterpret_cast<bf16x8*>(&buf[off_x0]) = cvt8(b0, b1);
        *reinterpret_cast<bf16x8*>(&buf[off_x1]) = cvt8(b2, b3);
        asm volatile("s_waitcnt lgkmcnt(0)" ::: "memory");
        __builtin_amdgcn_s_barrier();      // tile kt+1 visible to all waves
    }

    // final tile (kt = 15): compute only
    {
        #pragma unroll
        for (int kk = 0; kk < 2; ++kk) {
            bf16x8 af[4], bfr[2];
            #pragma unroll
            for (int mi = 0; mi < 4; ++mi)
                af[mi] = *reinterpret_cast<const bf16x8*>(
                    &buf[((a_base + kk * 64) ^ swz) + mi * 2048]);
            #pragma unroll
            for (int ni = 0; ni < 2; ++ni)
                bfr[ni] = *reinterpret_cast<const bf16x8*>(
                    &buf[((b_base + kk * 64) ^ swz) + ni * 2048]);
            #pragma unroll
            for (int mi = 0; mi < 4; ++mi)
                #pragma unroll
                for (int ni = 0; ni < 2; ++ni)
                    acc[mi][ni] = __builtin_amdgcn_mfma_f32_16x16x32_bf16(
                        af[mi], bfr[ni], acc[mi][ni], 0, 0, 0);
        }
    }

    // ---- epilogue: C/D col = lane&15 (o), row = (lane>>4)*4 + reg (b) ----
    const int s_sel = wm ? s1 : s0;
    const int col0 = nt * 128 + wn * 32 + (lane & 15);
    const int r0 = (lane >> 4) << 2;
    #pragma unroll
    for (int mi = 0; mi < 4; ++mi)
        #pragma unroll
        for (int ni = 0; ni < 2; ++ni)
            #pragma unroll
            for (int r = 0; r < 4; ++r) {
                int b = mi * 16 + r0 + r;
                out[((size_t)b * S_ + s_sel) * O_ + col0 + ni * 16] = acc[mi][ni][r];
            }
}

extern "C" void kernel_launch(void* const* d_in, const int* in_sizes, int n_in,
                              void* d_out, int out_size, void* d_ws, size_t ws_size,
                              hipStream_t stream) {
    const float* x  = (const float*)d_in[0];
    const int* lidx = (const int*)d_in[1];
    const float* w  = (const float*)d_in[2];
    float* out      = (float*)d_out;
    (void)d_ws; (void)ws_size;
    moshi_fused<<<dim3(72 * 8), dim3(512), 0, stream>>>(x, lidx, w, out);
}

// Round 11
// 56.293 us; speedup vs baseline: 1.5342x; 1.5281x over previous
//
#include <hip/hip_runtime.h>
#include <hip/hip_bf16.h>

#define B_ 64
#define S_ 128
#define D_ 1024
#define O_ 1024
#define L_ 16

typedef __bf16 bf16x8 __attribute__((ext_vector_type(8)));
typedef float f32x4 __attribute__((ext_vector_type(4)));

// ws layout (bytes):
//  [0, 33554432)        W' = bf16(w), row-major [16][1024][1024]
//  [33554432, 50331648) X' = bf16(x), row-major [64][128][1024]
//  [50331648]           npairs (int, 16-byte slot)
//  [50331664, +72*16)   pairs int4 {s0, s1, layer, 0}
#define WS_W   0ull
#define WS_X   33554432ull
#define WS_P   50331648ull
#define WS_NEED (50331664ull + 72ull * 16ull)

__device__ __forceinline__ unsigned f2bf2(float a, float b) {
    union { float f; unsigned u; } x{a}, y{b};
    unsigned lo = x.u + 0x7FFFu + ((x.u >> 16) & 1u);
    unsigned hi = y.u + 0x7FFFu + ((y.u >> 16) & 1u);
    return (lo >> 16) | (hi & 0xFFFF0000u);
}

__device__ __forceinline__ void gload16(const void* g, void* l) {
    __builtin_amdgcn_global_load_lds(
        (const __attribute__((address_space(1))) void*)g,
        (__attribute__((address_space(3))) void*)l, 16, 0, 0);
}

// ---- pass 1: pure linear fp32 -> bf16 cast (both sides fully coalesced).
// Thread handles float4 #(block*512 + tid) and #(block*512 + 256 + tid):
// every load instruction is 1 KB/wave contiguous, every store 512 B/wave.
// Block 0 lanes 0-15 also build the layer-grouped s-pairs.
__global__ __launch_bounds__(256) void moshi_convert(
    const float* __restrict__ x, const float* __restrict__ w,
    const int* __restrict__ lidx, unsigned char* __restrict__ ws) {
    if (blockIdx.x == 0 && threadIdx.x < 16) {
        int t = threadIdx.x;
        int cnt[16];
        #pragma unroll 1
        for (int m = 0; m < 16; ++m) cnt[m] = 0;
        for (int s = 0; s < S_; ++s) ++cnt[lidx[s]];
        int off = 0;
        for (int m = 0; m < t; ++m) off += (cnt[m] + 1) >> 1;
        int4* pairs = (int4*)(ws + WS_P + 16);
        int k = 0, prev = -1;
        for (int s = 0; s < S_; ++s) {
            if (lidx[s] == t) {
                if (k & 1) pairs[off + (k >> 1)] = make_int4(prev, s, t, 0);
                prev = s; ++k;
            }
        }
        if (k & 1) pairs[off + (k >> 1)] = make_int4(prev, prev, t, 0);
        if (t == 0) {
            int tot = 0;
            for (int m = 0; m < 16; ++m) tot += (cnt[m] + 1) >> 1;
            *(int*)(ws + WS_P) = tot;
        }
    }
    // W: 4194304 float4s -> blocks [0, 8192); x: 2097152 -> blocks [8192, 12288)
    const float4* src;
    uint2* dst;
    unsigned i0 = blockIdx.x * 512 + threadIdx.x;
    if (blockIdx.x < 8192) {
        src = reinterpret_cast<const float4*>(w);
        dst = reinterpret_cast<uint2*>(ws + WS_W);
    } else {
        src = reinterpret_cast<const float4*>(x);
        dst = reinterpret_cast<uint2*>(ws + WS_X);
        i0 -= 4194304u;
    }
    float4 v0 = src[i0];
    float4 v1 = src[i0 + 256];
    dst[i0]       = make_uint2(f2bf2(v0.x, v0.y), f2bf2(v0.z, v0.w));
    dst[i0 + 256] = make_uint2(f2bf2(v1.x, v1.y), f2bf2(v1.z, v1.w));
}

// ---- pass 2: paired GEMM (R6 structure, proven). Tile M=128 (2s x 64b) x
// N=128, BK=64, 8 waves (2 wm x 4 wn), 64x32 per wave. gload_lds with the
// XOR swizzle applied to the per-lane GLOBAL source address (m173): LDS dest
// stays linear, LDS content ends up identical to the pre-swizzled-tile version.
__global__ __launch_bounds__(512, 4) void moshi_gemm_n128(
    const unsigned char* __restrict__ ws, float* __restrict__ out) {
    __shared__ __align__(16) unsigned char lw[16384];   // 128(o) x 64(k) bf16, swizzled
    __shared__ __align__(16) unsigned char lx[16384];   // s0: rows 0-63, s1: rows 64-127

    // bijective XCD-chunk swizzle: grid 576 = 8 chunks of 72 (9 pairs x 8 nt)
    const int bid = (blockIdx.x & 7) * 72 + (blockIdx.x >> 3);
    const int pi = bid >> 3;
    const int nt = bid & 7;
    const int np = *reinterpret_cast<const int*>(ws + WS_P);
    if (pi >= np) return;   // block-uniform exit before any barrier
    const int4 pr = *reinterpret_cast<const int4*>(ws + WS_P + 16 + 16ull * pi);
    const int s0 = pr.x, s1 = pr.y, l = pr.z;

    const int tid = threadIdx.x, lane = tid & 63, wid = tid >> 6;

    // staging source addresses: thread covers LDS byte tid*16 (row = tid/8,
    // col16 = (tid&7)*16) of each 128-row tile half; swizzle in the source.
    const int rowq = tid >> 3;                 // 0..63
    const int c16  = (tid & 7) << 4;
    const int csw  = c16 ^ ((rowq & 7) << 4);  // key identical for row+64
    const unsigned char* wsrc0 = ws + WS_W
        + ((size_t)(l * 1024 + nt * 128 + rowq) << 11) + csw;
    const unsigned char* wsrc1 = wsrc0 + ((size_t)64 << 11);
    const unsigned char* xsrc0 = ws + WS_X
        + ((size_t)(rowq * 128 + s0) << 11) + csw;
    const unsigned char* xsrc1 = ws + WS_X
        + ((size_t)(rowq * 128 + s1) << 11) + csw;

    // fragment read addressing (proven R6 mapping, LDS-side XOR swizzle)
    const int wm = wid >> 2, wn = wid & 3;
    const int swz = (lane & 7) << 4;
    const int kb  = (lane >> 4) << 4;
    const int a_base = (wm * 64 + (lane & 15)) * 128 + kb;   // x rows
    const int b_base = (wn * 32 + (lane & 15)) * 128 + kb;   // W rows

    f32x4 acc[4][2];
    #pragma unroll
    for (int i = 0; i < 4; ++i)
        #pragma unroll
        for (int j = 0; j < 2; ++j) acc[i][j] = (f32x4)0.0f;

    #pragma unroll 1
    for (int kt = 0; kt < 16; ++kt) {
        __syncthreads();
        gload16(wsrc0 + kt * 128, lw + tid * 16);
        gload16(wsrc1 + kt * 128, lw + tid * 16 + 8192);
        gload16(xsrc0 + kt * 128, lx + tid * 16);
        gload16(xsrc1 + kt * 128, lx + tid * 16 + 8192);
        __syncthreads();
        #pragma unroll
        for (int kk = 0; kk < 2; ++kk) {
            bf16x8 af[4], bfr[2];
            #pragma unroll
            for (int mi = 0; mi < 4; ++mi)
                af[mi] = *reinterpret_cast<const bf16x8*>(
                    lx + (((a_base + kk * 64) ^ swz) + mi * 2048));
            #pragma unroll
            for (int ni = 0; ni < 2; ++ni)
                bfr[ni] = *reinterpret_cast<const bf16x8*>(
                    lw + (((b_base + kk * 64) ^ swz) + ni * 2048));
            #pragma unroll
            for (int mi = 0; mi < 4; ++mi)
                #pragma unroll
                for (int ni = 0; ni < 2; ++ni)
                    acc[mi][ni] = __builtin_amdgcn_mfma_f32_16x16x32_bf16(
                        af[mi], bfr[ni], acc[mi][ni], 0, 0, 0);
        }
    }

    // epilogue: C/D col = lane&15 (o), row = (lane>>4)*4 + reg (b)
    const int s_sel = wm ? s1 : s0;
    const int col0 = nt * 128 + wn * 32 + (lane & 15);
    const int r0 = (lane >> 4) << 2;
    #pragma unroll
    for (int mi = 0; mi < 4; ++mi)
        #pragma unroll
        for (int ni = 0; ni < 2; ++ni)
            #pragma unroll
            for (int r = 0; r < 4; ++r) {
                int b = mi * 16 + r0 + r;
                out[((size_t)b * S_ + s_sel) * O_ + col0 + ni * 16] = acc[mi][ni][r];
            }
}

// ---- fallback (round-1 kernel) if ws is too small ----
__global__ __launch_bounds__(256) void moshi_flin_fallback(
    const float* __restrict__ x, const int* __restrict__ lidx,
    const float* __restrict__ w, float* __restrict__ out) {
    __shared__ __align__(16) unsigned char lxs[64 * 128];
    __shared__ __align__(16) unsigned char lws[128 * 128];
    const int bid = blockIdx.x;
    const int s = bid >> 3, n0 = (bid & 7) << 7;
    const int tid = threadIdx.x, lane = tid & 63, wid = tid >> 6;
    const int idx = lidx[s];
    const float* wb = w + (size_t)idx * O_ * D_ + (size_t)n0 * D_;
    const float* xb = x + (size_t)s * D_;
    const int swz = (lane & 7) << 4;
    const int kb = (lane >> 4) << 4;
    const int a_base = (lane & 15) * 128 + kb;
    const int b_base = (wid * 32 + (lane & 15)) * 128 + kb;
    f32x4 acc[4][2];
    #pragma unroll
    for (int i = 0; i < 4; ++i)
        #pragma unroll
        for (int j = 0; j < 2; ++j) acc[i][j] = (f32x4)0.0f;
    for (int kt = 0; kt < D_; kt += 64) {
        __syncthreads();
        #pragma unroll
        for (int p = 0; p < 4; ++p) {
            int f = tid + p * 256, row = f >> 4, cc = (f & 15) << 2;
            const float4 v = *reinterpret_cast<const float4*>(
                xb + (size_t)row * (S_ * D_) + kt + cc);
            uint2 pk = { f2bf2(v.x, v.y), f2bf2(v.z, v.w) };
            *reinterpret_cast<uint2*>(&lxs[(row * 128 + cc * 2) ^ ((row & 7) << 4)]) = pk;
        }
        #pragma unroll
        for (int p = 0; p < 8; ++p) {
            int f = tid + p * 256, row = f >> 4, cc = (f & 15) << 2;
            const float4 v = *reinterpret_cast<const float4*>(
                wb + (size_t)row * D_ + kt + cc);
            uint2 pk = { f2bf2(v.x, v.y), f2bf2(v.z, v.w) };
            *reinterpret_cast<uint2*>(&lws[(row * 128 + cc * 2) ^ ((row & 7) << 4)]) = pk;
        }
        __syncthreads();
        #pragma unroll
        for (int kk = 0; kk < 2; ++kk) {
            bf16x8 af[4], bfr[2];
            #pragma unroll
            for (int mi = 0; mi < 4; ++mi)
                af[mi] = *reinterpret_cast<const bf16x8*>(
                    &lxs[(((a_base + kk * 64) ^ swz) + mi * 2048)]);
            #pragma unroll
            for (int ni = 0; ni < 2; ++ni)
                bfr[ni] = *reinterpret_cast<const bf16x8*>(
                    &lws[(((b_base + kk * 64) ^ swz) + ni * 2048)]);
            #pragma unroll
            for (int mi = 0; mi < 4; ++mi)
                #pragma unroll
                for (int ni = 0; ni < 2; ++ni)
                    acc[mi][ni] = __builtin_amdgcn_mfma_f32_16x16x32_bf16(
                        af[mi], bfr[ni], acc[mi][ni], 0, 0, 0);
        }
    }
    float* ob = out + (size_t)s * O_ + n0 + wid * 32 + (lane & 15);
    const int r0 = (lane >> 4) << 2;
    #pragma unroll
    for (int mi = 0; mi < 4; ++mi)
        #pragma unroll
        for (int ni = 0; ni < 2; ++ni)
            #pragma unroll
            for (int r = 0; r < 4; ++r) {
                int b = mi * 16 + r0 + r;
                ob[(size_t)b * (S_ * O_) + ni * 16] = acc[mi][ni][r];
            }
}

extern "C" void kernel_launch(void* const* d_in, const int* in_sizes, int n_in,
                              void* d_out, int out_size, void* d_ws, size_t ws_size,
                              hipStream_t stream) {
    const float* x  = (const float*)d_in[0];
    const int* lidx = (const int*)d_in[1];
    const float* w  = (const float*)d_in[2];
    float* out      = (float*)d_out;

    if (ws_size < WS_NEED) {
        moshi_flin_fallback<<<dim3(128 * 8), dim3(256), 0, stream>>>(x, lidx, w, out);
        return;
    }
    unsigned char* ws = (unsigned char*)d_ws;
    // 6291456 float4s total, 512 per block -> 12288 blocks (W: first 8192)
    moshi_convert<<<dim3(12288), dim3(256), 0, stream>>>(x, w, lidx, ws);
    // 72 pair slots x 8 n-tiles, 512 threads
    moshi_gemm_n128<<<dim3(72 * 8), dim3(512), 0, stream>>>(ws, out);
}